// Round 4
// baseline (608.549 us; speedup 1.0000x reference)
//
#include <hip/hip_runtime.h>
#include <hip/hip_bf16.h>
#include <stdint.h>

// Problem constants (K=4, OUT=4096, IN=4096, B=2, S=2048)
#define DIM_M 4096   // B*S rows of x
#define DIM_N 4096   // OUT
#define DIM_K 4096   // IN
#define BASE_STRIDE (DIM_N * DIM_K)  // elements per basis

typedef __bf16 bf16x8 __attribute__((ext_vector_type(8)));
typedef float floatx4 __attribute__((ext_vector_type(4)));
typedef unsigned short ushort8 __attribute__((ext_vector_type(8)));

typedef const __attribute__((address_space(1))) void* gptr1;
typedef __attribute__((address_space(3))) void* lptr3;

__device__ __forceinline__ void async_copy16(const void* g, void* l) {
    // width=16 global->LDS DMA; LDS dest is wave-uniform base + lane*16
    __builtin_amdgcn_global_load_lds((gptr1)g, (lptr3)l, 16, 0, 0);
}

__device__ __forceinline__ unsigned short f2bf(float f) {
    uint32_t u = __float_as_uint(f);
    uint32_t r = (u + 0x7FFFu + ((u >> 16) & 1u)) >> 16;  // RNE
    return (unsigned short)r;
}

// ---------------------------------------------------------------------------
// Fused prologue: blocks [0, 8192) build W_bf16 = bf16(sum_k alpha_k*bases_k);
// blocks [8192, 16384) convert x fp32 -> bf16. 8 elems/thread, 16B stores.
// ---------------------------------------------------------------------------
__global__ __launch_bounds__(256) void prep_kernel(
        const int* __restrict__ bases, const float* __restrict__ alphas,
        const float* __restrict__ x,
        unsigned short* __restrict__ Wb, unsigned short* __restrict__ Xb) {
    const int bid = blockIdx.x;
    if (bid < 8192) {
        const long e = ((long)bid * 256 + threadIdx.x) * 8;
        const float a0 = alphas[0], a1 = alphas[1], a2 = alphas[2], a3 = alphas[3];
        const int4 p0 = *(const int4*)(bases + e);
        const int4 p1 = *(const int4*)(bases + e + 4);
        const int4 q0 = *(const int4*)(bases + BASE_STRIDE + e);
        const int4 q1 = *(const int4*)(bases + BASE_STRIDE + e + 4);
        const int4 r0 = *(const int4*)(bases + 2L * BASE_STRIDE + e);
        const int4 r1 = *(const int4*)(bases + 2L * BASE_STRIDE + e + 4);
        const int4 s0 = *(const int4*)(bases + 3L * BASE_STRIDE + e);
        const int4 s1 = *(const int4*)(bases + 3L * BASE_STRIDE + e + 4);
        ushort8 o;
        o[0] = f2bf(a0 * p0.x + a1 * q0.x + a2 * r0.x + a3 * s0.x);
        o[1] = f2bf(a0 * p0.y + a1 * q0.y + a2 * r0.y + a3 * s0.y);
        o[2] = f2bf(a0 * p0.z + a1 * q0.z + a2 * r0.z + a3 * s0.z);
        o[3] = f2bf(a0 * p0.w + a1 * q0.w + a2 * r0.w + a3 * s0.w);
        o[4] = f2bf(a0 * p1.x + a1 * q1.x + a2 * r1.x + a3 * s1.x);
        o[5] = f2bf(a0 * p1.y + a1 * q1.y + a2 * r1.y + a3 * s1.y);
        o[6] = f2bf(a0 * p1.z + a1 * q1.z + a2 * r1.z + a3 * s1.z);
        o[7] = f2bf(a0 * p1.w + a1 * q1.w + a2 * r1.w + a3 * s1.w);
        *(ushort8*)(Wb + e) = o;
    } else {
        const long e = ((long)(bid - 8192) * 256 + threadIdx.x) * 8;
        const float4 v0 = *(const float4*)(x + e);
        const float4 v1 = *(const float4*)(x + e + 4);
        ushort8 o;
        o[0] = f2bf(v0.x); o[1] = f2bf(v0.y); o[2] = f2bf(v0.z); o[3] = f2bf(v0.w);
        o[4] = f2bf(v1.x); o[5] = f2bf(v1.y); o[6] = f2bf(v1.z); o[7] = f2bf(v1.w);
        *(ushort8*)(Xb + e) = o;
    }
}

// ---------------------------------------------------------------------------
// Main GEMM: C[m][n] = sum_k A[m][k] * Bt[n][k]   (A=Xbf16, Bt=Wbf16)
// 128x128 block tile, 256 threads (4 waves, 2x2), BK=32, 16x16x32 bf16 MFMA,
// 4x4 accumulators/wave.
//
// R4 pipeline: global_load_lds DMA staging (no VGPR round-trip, no ds_write
// on the LDS issue pipe) + double-buffered LDS + ONE barrier per iter.
// DMA for tile k+1 issues immediately AFTER the barrier; the next barrier's
// vmcnt(0) drain lands after the MFMA block (~600 CU-cycles of cover for the
// ~200cy L2-hit latency). ds_read (lgkmcnt) does not wait on the DMA (vmcnt).
//
// LDS XOR swizzle (conflict-free, verified R2): 16B slot (row, c) stored at
// row*4 + (c ^ ((row>>1)&3)); applied by permuting the GLOBAL source chunk
// (qc) since DMA forces LDS dst = base + lane*16. Readers use
// swz = quad ^ ((l16>>1)&3).
// ---------------------------------------------------------------------------
__global__ __launch_bounds__(256) void gemm_bt_kernel(
        const unsigned short* __restrict__ A, const unsigned short* __restrict__ Bt,
        float* __restrict__ C) {
    __shared__ unsigned short sA[2 * 128 * 32];
    __shared__ unsigned short sB[2 * 128 * 32];

    const int t = threadIdx.x;
    const int wave = t >> 6, lane = t & 63;
    const int wm = (wave >> 1) * 64;   // wave row offset in tile
    const int wn = (wave & 1) * 64;    // wave col offset in tile
    const int quad = lane >> 4, l16 = lane & 15;

    const int mBase = blockIdx.y * 128;
    const int nBase = blockIdx.x * 128;

    // Staging addresses: thread t owns LDS slot t (row t>>2, stored chunk t&3),
    // filled with logical chunk qc = (t&3)^((t>>3)&3) from global.
    const int srow = t >> 2;                      // 0..63
    const int qc = (t & 3) ^ ((t >> 3) & 3);      // swizzled source chunk
    const unsigned short* gA0 = A + (size_t)(mBase + srow) * DIM_K + qc * 8;
    const unsigned short* gA1 = gA0 + (size_t)64 * DIM_K;
    const unsigned short* gB0 = Bt + (size_t)(nBase + srow) * DIM_K + qc * 8;
    const unsigned short* gB1 = gB0 + (size_t)64 * DIM_K;
    unsigned short* lA0 = sA + t * 8;
    unsigned short* lA1 = sA + 2048 + t * 8;
    unsigned short* lB0 = sB + t * 8;
    unsigned short* lB1 = sB + 2048 + t * 8;

    // Fragment read offsets within one buffer
    const int swz = quad ^ ((l16 >> 1) & 3);
    const int aoff0 = (wm + l16) * 32 + swz * 8;
    const int boff0 = (wn + l16) * 32 + swz * 8;

    floatx4 acc[4][4] = {};

    // ---- prologue: DMA tile 0 into buffer 0, drain, go ----
    async_copy16(gA0, lA0);
    async_copy16(gA1, lA1);
    async_copy16(gB0, lB0);
    async_copy16(gB1, lB1);
    gA0 += 32; gA1 += 32; gB0 += 32; gB1 += 32;
    __syncthreads();

    int p = 0;
    for (int kt = 0; kt < DIM_K; kt += 32) {
        // Prefetch tile k+1 into the OTHER buffer, right after the barrier.
        // Its last readers finished before that barrier, so no WAR hazard.
        if ((kt + 32) < DIM_K) {
            const int q = (p ^ 1) * 4096;
            async_copy16(gA0, lA0 + q);
            async_copy16(gA1, lA1 + q);
            async_copy16(gB0, lB0 + q);
            async_copy16(gB1, lB1 + q);
            gA0 += 32; gA1 += 32; gB0 += 32; gB1 += 32;
        }

        const unsigned short* bufA = sA + p * 4096;
        const unsigned short* bufB = sB + p * 4096;
        bf16x8 a[4], b[4];
#pragma unroll
        for (int i = 0; i < 4; i++)
            a[i] = *(const bf16x8*)(bufA + aoff0 + i * 16 * 32);
#pragma unroll
        for (int j = 0; j < 4; j++)
            b[j] = *(const bf16x8*)(bufB + boff0 + j * 16 * 32);

#pragma unroll
        for (int i = 0; i < 4; i++)
#pragma unroll
            for (int j = 0; j < 4; j++)
                acc[i][j] = __builtin_amdgcn_mfma_f32_16x16x32_bf16(
                    a[i], b[j], acc[i][j], 0, 0, 0);

        __syncthreads();   // vmcnt(0) drain lands HERE, after the MFMA block
        p ^= 1;
    }

    // Epilogue: C/D layout col=lane&15, row=quad*4+reg  [measured m89/m91]
#pragma unroll
    for (int i = 0; i < 4; i++) {
#pragma unroll
        for (int j = 0; j < 4; j++) {
#pragma unroll
            for (int r = 0; r < 4; r++) {
                const int row = mBase + wm + i * 16 + quad * 4 + r;
                const int col = nBase + wn + j * 16 + l16;
                C[(size_t)row * DIM_N + col] = acc[i][j][r];
            }
        }
    }
}

// ---------------------------------------------------------------------------
// Fallback (only if workspace too small): direct fp32, one thread per output
// ---------------------------------------------------------------------------
__global__ __launch_bounds__(256) void naive_kernel(
        const float* __restrict__ x, const float* __restrict__ alphas,
        const int* __restrict__ bases, float* __restrict__ out) {
    const long o = (long)blockIdx.x * 256 + threadIdx.x;
    const int m = (int)(o >> 12), n = (int)(o & 4095);
    const float a0 = alphas[0], a1 = alphas[1], a2 = alphas[2], a3 = alphas[3];
    const float* xr = x + (long)m * DIM_K;
    const int* b0 = bases + (long)n * DIM_K;
    const int* b1 = b0 + BASE_STRIDE;
    const int* b2 = b1 + BASE_STRIDE;
    const int* b3 = b2 + BASE_STRIDE;
    float acc = 0.f;
    for (int i = 0; i < DIM_K; i++) {
        float w = a0 * b0[i] + a1 * b1[i] + a2 * b2[i] + a3 * b3[i];
        acc += xr[i] * w;
    }
    out[o] = acc;
}

extern "C" void kernel_launch(void* const* d_in, const int* in_sizes, int n_in,
                              void* d_out, int out_size, void* d_ws, size_t ws_size,
                              hipStream_t stream) {
    const float* x      = (const float*)d_in[0];
    const float* alphas = (const float*)d_in[1];
    const int*   bases  = (const int*)d_in[2];
    float* out = (float*)d_out;

    const size_t need = (size_t)2 * DIM_N * DIM_K + (size_t)2 * DIM_M * DIM_K; // 64 MB
    if (ws_size >= need) {
        unsigned short* Wb = (unsigned short*)d_ws;                    // [4096][4096] bf16
        unsigned short* Xb = (unsigned short*)d_ws + (size_t)DIM_N * DIM_K;
        prep_kernel<<<16384, 256, 0, stream>>>(bases, alphas, x, Wb, Xb);
        gemm_bt_kernel<<<dim3(DIM_N / 128, DIM_M / 128), 256, 0, stream>>>(Xb, Wb, out);
    } else {
        naive_kernel<<<(DIM_M * DIM_N) / 256, 256, 0, stream>>>(x, alphas, bases, out);
    }
}

// Round 5
// 594.706 us; speedup vs baseline: 1.0233x; 1.0233x over previous
//
#include <hip/hip_runtime.h>
#include <hip/hip_bf16.h>
#include <stdint.h>

// Problem constants (K=4, OUT=4096, IN=4096, B=2, S=2048)
#define DIM_M 4096   // B*S rows of x
#define DIM_N 4096   // OUT
#define DIM_K 4096   // IN
#define BASE_STRIDE (DIM_N * DIM_K)  // elements per basis

typedef __bf16 bf16x8 __attribute__((ext_vector_type(8)));
typedef float floatx16 __attribute__((ext_vector_type(16)));
typedef unsigned short ushort8 __attribute__((ext_vector_type(8)));

__device__ __forceinline__ unsigned short f2bf(float f) {
    uint32_t u = __float_as_uint(f);
    uint32_t r = (u + 0x7FFFu + ((u >> 16) & 1u)) >> 16;  // RNE
    return (unsigned short)r;
}

// ---------------------------------------------------------------------------
// Fused prologue: blocks [0, 8192) build W_bf16 = bf16(sum_k alpha_k*bases_k);
// blocks [8192, 16384) convert x fp32 -> bf16. 8 elems/thread, 16B stores.
// ---------------------------------------------------------------------------
__global__ __launch_bounds__(256) void prep_kernel(
        const int* __restrict__ bases, const float* __restrict__ alphas,
        const float* __restrict__ x,
        unsigned short* __restrict__ Wb, unsigned short* __restrict__ Xb) {
    const int bid = blockIdx.x;
    if (bid < 8192) {
        const long e = ((long)bid * 256 + threadIdx.x) * 8;
        const float a0 = alphas[0], a1 = alphas[1], a2 = alphas[2], a3 = alphas[3];
        const int4 p0 = *(const int4*)(bases + e);
        const int4 p1 = *(const int4*)(bases + e + 4);
        const int4 q0 = *(const int4*)(bases + BASE_STRIDE + e);
        const int4 q1 = *(const int4*)(bases + BASE_STRIDE + e + 4);
        const int4 r0 = *(const int4*)(bases + 2L * BASE_STRIDE + e);
        const int4 r1 = *(const int4*)(bases + 2L * BASE_STRIDE + e + 4);
        const int4 s0 = *(const int4*)(bases + 3L * BASE_STRIDE + e);
        const int4 s1 = *(const int4*)(bases + 3L * BASE_STRIDE + e + 4);
        ushort8 o;
        o[0] = f2bf(a0 * p0.x + a1 * q0.x + a2 * r0.x + a3 * s0.x);
        o[1] = f2bf(a0 * p0.y + a1 * q0.y + a2 * r0.y + a3 * s0.y);
        o[2] = f2bf(a0 * p0.z + a1 * q0.z + a2 * r0.z + a3 * s0.z);
        o[3] = f2bf(a0 * p0.w + a1 * q0.w + a2 * r0.w + a3 * s0.w);
        o[4] = f2bf(a0 * p1.x + a1 * q1.x + a2 * r1.x + a3 * s1.x);
        o[5] = f2bf(a0 * p1.y + a1 * q1.y + a2 * r1.y + a3 * s1.y);
        o[6] = f2bf(a0 * p1.z + a1 * q1.z + a2 * r1.z + a3 * s1.z);
        o[7] = f2bf(a0 * p1.w + a1 * q1.w + a2 * r1.w + a3 * s1.w);
        *(ushort8*)(Wb + e) = o;
    } else {
        const long e = ((long)(bid - 8192) * 256 + threadIdx.x) * 8;
        const float4 v0 = *(const float4*)(x + e);
        const float4 v1 = *(const float4*)(x + e + 4);
        ushort8 o;
        o[0] = f2bf(v0.x); o[1] = f2bf(v0.y); o[2] = f2bf(v0.z); o[3] = f2bf(v0.w);
        o[4] = f2bf(v1.x); o[5] = f2bf(v1.y); o[6] = f2bf(v1.z); o[7] = f2bf(v1.w);
        *(ushort8*)(Xb + e) = o;
    }
}

// ---------------------------------------------------------------------------
// Main GEMM: C[m][n] = sum_k A[m][k] * Bt[n][k]   (A=Xbf16, Bt=Wbf16)
// 128x128 block tile, 256 threads (4 waves, 2x2 of 64x64), BK=32.
//
// R5: R3's reg-staged double-buffer single-barrier pipeline (best measured:
// 198us) + 32x32x16 bf16 MFMA (2x2 accs/wave, 8 MFMA/iter instead of 16;
// higher per-inst throughput, m06) + XCD-aware block swizzle (XCD = bid&7
// round-robin heuristic: each XCD owns a 4-col n-band so its ~32 concurrent
// blocks share one 1MB L2-resident B band while streaming A from LLC).
//
// LDS XOR swizzle (conflict-free, verified R2): 16B slot (row,c) stored at
// row*4 + (c ^ ((row>>1)&3)). Writers: thread t owns slot t, fills logical
// chunk qc=(t&3)^((t>>3)&3). Readers (32x32 frags): lane l -> row base+l31,
// logical chunk c = 2h + (l>>5), stored at c ^ ((l31>>1)&3).
//
// 32x32x16 layouts: A/B operand: m(or n)=lane&31, k=(lane>>5)*8+j [inferred
// by symmetry from verified 16x16 layout]; C/D: col=lane&31,
// row=(reg&3)+8*(reg>>2)+4*(lane>>5) [HW-verified m74/m101].
// ---------------------------------------------------------------------------
__global__ __launch_bounds__(256, 4) void gemm_bt_kernel(
        const unsigned short* __restrict__ A, const unsigned short* __restrict__ Bt,
        float* __restrict__ C) {
    __shared__ unsigned short sA[2 * 128 * 32];
    __shared__ unsigned short sB[2 * 128 * 32];

    const int t = threadIdx.x;
    const int wave = t >> 6, lane = t & 63;
    const int wm = (wave >> 1) * 64;   // wave row offset in tile
    const int wn = (wave & 1) * 64;    // wave col offset in tile
    const int l31 = lane & 31, g = lane >> 5;

    // XCD-aware swizzle: xcd = f&7 (dispatch round-robin heuristic),
    // local = f>>3 in [0,128): tm = local&31, tn = xcd*4 + local>>5.
    const int f = blockIdx.x;
    const int tm = (f >> 3) & 31;
    const int tn = (f & 7) * 4 + (f >> 8);
    const int mBase = tm * 128;
    const int nBase = tn * 128;

    // Staging addresses (thread t owns LDS slot t: row t>>2, stored chunk t&3)
    const int srow = t >> 2;                      // 0..63
    const int qc = (t & 3) ^ ((t >> 3) & 3);      // swizzled source chunk
    const unsigned short* gA0 = A + (size_t)(mBase + srow) * DIM_K + qc * 8;
    const unsigned short* gA1 = gA0 + (size_t)64 * DIM_K;
    const unsigned short* gB0 = Bt + (size_t)(nBase + srow) * DIM_K + qc * 8;
    const unsigned short* gB1 = gB0 + (size_t)64 * DIM_K;

    // Fragment read offsets within one buffer (elements).
    // a[i][h] at (wm + i*32 + l31)*32 + ((2h+g)^s)*8 ; b[j][h] same with wn.
    const int s = (l31 >> 1) & 3;
    const int c0 = ((0 + g) ^ s) * 8;   // h=0 chunk offset
    const int c1 = ((2 + g) ^ s) * 8;   // h=1 chunk offset
    const int arow = (wm + l31) * 32;
    const int brow = (wn + l31) * 32;

    floatx16 acc[2][2] = {};

    // ---- prologue: tile 0 -> regs -> LDS buf 0 ----
    ushort8 rA0 = *(const ushort8*)gA0;
    ushort8 rA1 = *(const ushort8*)gA1;
    ushort8 rB0 = *(const ushort8*)gB0;
    ushort8 rB1 = *(const ushort8*)gB1;
    gA0 += 32; gA1 += 32; gB0 += 32; gB1 += 32;
    *(ushort8*)(sA + t * 8) = rA0;
    *(ushort8*)(sA + 2048 + t * 8) = rA1;
    *(ushort8*)(sB + t * 8) = rB0;
    *(ushort8*)(sB + 2048 + t * 8) = rB1;
    __syncthreads();

    int p = 0;
    for (int kt = 0; kt < DIM_K; kt += 32) {
        const bool more = (kt + 32) < DIM_K;
        if (more) {
            rA0 = *(const ushort8*)gA0;
            rA1 = *(const ushort8*)gA1;
            rB0 = *(const ushort8*)gB0;
            rB1 = *(const ushort8*)gB1;
            gA0 += 32; gA1 += 32; gB0 += 32; gB1 += 32;
        }

        const unsigned short* bufA = sA + p * 4096;
        const unsigned short* bufB = sB + p * 4096;
        bf16x8 a[2][2], b[2][2];
#pragma unroll
        for (int i = 0; i < 2; i++) {
            a[i][0] = *(const bf16x8*)(bufA + arow + i * 32 * 32 + c0);
            a[i][1] = *(const bf16x8*)(bufA + arow + i * 32 * 32 + c1);
        }
#pragma unroll
        for (int j = 0; j < 2; j++) {
            b[j][0] = *(const bf16x8*)(bufB + brow + j * 32 * 32 + c0);
            b[j][1] = *(const bf16x8*)(bufB + brow + j * 32 * 32 + c1);
        }

#pragma unroll
        for (int h = 0; h < 2; h++)
#pragma unroll
            for (int i = 0; i < 2; i++)
#pragma unroll
                for (int j = 0; j < 2; j++)
                    acc[i][j] = __builtin_amdgcn_mfma_f32_32x32x16_bf16(
                        a[i][h], b[j][h], acc[i][j], 0, 0, 0);

        if (more) {
            unsigned short* wA = sA + (p ^ 1) * 4096;
            unsigned short* wB = sB + (p ^ 1) * 4096;
            *(ushort8*)(wA + t * 8) = rA0;          // vmcnt wait lands here,
            *(ushort8*)(wA + 2048 + t * 8) = rA1;   // after the MFMA block
            *(ushort8*)(wB + t * 8) = rB0;
            *(ushort8*)(wB + 2048 + t * 8) = rB1;
        }
        __syncthreads();   // single barrier per iter
        p ^= 1;
    }

    // Epilogue: 32x32 C/D layout col=lane&31, row=(r&3)+8*(r>>2)+4*g
#pragma unroll
    for (int i = 0; i < 2; i++) {
#pragma unroll
        for (int j = 0; j < 2; j++) {
#pragma unroll
            for (int r = 0; r < 16; r++) {
                const int row = mBase + wm + i * 32 + (r & 3) + 8 * (r >> 2) + 4 * g;
                const int col = nBase + wn + j * 32 + l31;
                C[(size_t)row * DIM_N + col] = acc[i][j][r];
            }
        }
    }
}

// ---------------------------------------------------------------------------
// Fallback (only if workspace too small): direct fp32, one thread per output
// ---------------------------------------------------------------------------
__global__ __launch_bounds__(256) void naive_kernel(
        const float* __restrict__ x, const float* __restrict__ alphas,
        const int* __restrict__ bases, float* __restrict__ out) {
    const long o = (long)blockIdx.x * 256 + threadIdx.x;
    const int m = (int)(o >> 12), n = (int)(o & 4095);
    const float a0 = alphas[0], a1 = alphas[1], a2 = alphas[2], a3 = alphas[3];
    const float* xr = x + (long)m * DIM_K;
    const int* b0 = bases + (long)n * DIM_K;
    const int* b1 = b0 + BASE_STRIDE;
    const int* b2 = b1 + BASE_STRIDE;
    const int* b3 = b2 + BASE_STRIDE;
    float acc = 0.f;
    for (int i = 0; i < DIM_K; i++) {
        float w = a0 * b0[i] + a1 * b1[i] + a2 * b2[i] + a3 * b3[i];
        acc += xr[i] * w;
    }
    out[o] = acc;
}

extern "C" void kernel_launch(void* const* d_in, const int* in_sizes, int n_in,
                              void* d_out, int out_size, void* d_ws, size_t ws_size,
                              hipStream_t stream) {
    const float* x      = (const float*)d_in[0];
    const float* alphas = (const float*)d_in[1];
    const int*   bases  = (const int*)d_in[2];
    float* out = (float*)d_out;

    const size_t need = (size_t)2 * DIM_N * DIM_K + (size_t)2 * DIM_M * DIM_K; // 64 MB
    if (ws_size >= need) {
        unsigned short* Wb = (unsigned short*)d_ws;                    // [4096][4096] bf16
        unsigned short* Xb = (unsigned short*)d_ws + (size_t)DIM_N * DIM_K;
        prep_kernel<<<16384, 256, 0, stream>>>(bases, alphas, x, Wb, Xb);
        gemm_bt_kernel<<<1024, 256, 0, stream>>>(Xb, Wb, out);
    } else {
        naive_kernel<<<(DIM_M * DIM_N) / 256, 256, 0, stream>>>(x, alphas, bases, out);
    }
}

// Round 6
// 583.468 us; speedup vs baseline: 1.0430x; 1.0193x over previous
//
#include <hip/hip_runtime.h>
#include <hip/hip_bf16.h>
#include <stdint.h>

// Problem constants (K=4, OUT=4096, IN=4096, B=2, S=2048)
#define DIM_M 4096   // B*S rows of x
#define DIM_N 4096   // OUT
#define DIM_K 4096   // IN
#define BASE_STRIDE (DIM_N * DIM_K)  // elements per basis

#define RS 40        // LDS row stride in elements (80 B = 20 banks, pad 64B+16B)

typedef __bf16 bf16x8 __attribute__((ext_vector_type(8)));
typedef float floatx16 __attribute__((ext_vector_type(16)));
typedef unsigned short ushort8 __attribute__((ext_vector_type(8)));

__device__ __forceinline__ unsigned short f2bf(float f) {
    uint32_t u = __float_as_uint(f);
    uint32_t r = (u + 0x7FFFu + ((u >> 16) & 1u)) >> 16;  // RNE
    return (unsigned short)r;
}

// ---------------------------------------------------------------------------
// Fused prologue: blocks [0, 8192) build W_bf16 = bf16(sum_k alpha_k*bases_k);
// blocks [8192, 16384) convert x fp32 -> bf16. 8 elems/thread, 16B stores.
// ---------------------------------------------------------------------------
__global__ __launch_bounds__(256) void prep_kernel(
        const int* __restrict__ bases, const float* __restrict__ alphas,
        const float* __restrict__ x,
        unsigned short* __restrict__ Wb, unsigned short* __restrict__ Xb) {
    const int bid = blockIdx.x;
    if (bid < 8192) {
        const long e = ((long)bid * 256 + threadIdx.x) * 8;
        const float a0 = alphas[0], a1 = alphas[1], a2 = alphas[2], a3 = alphas[3];
        const int4 p0 = *(const int4*)(bases + e);
        const int4 p1 = *(const int4*)(bases + e + 4);
        const int4 q0 = *(const int4*)(bases + BASE_STRIDE + e);
        const int4 q1 = *(const int4*)(bases + BASE_STRIDE + e + 4);
        const int4 r0 = *(const int4*)(bases + 2L * BASE_STRIDE + e);
        const int4 r1 = *(const int4*)(bases + 2L * BASE_STRIDE + e + 4);
        const int4 s0 = *(const int4*)(bases + 3L * BASE_STRIDE + e);
        const int4 s1 = *(const int4*)(bases + 3L * BASE_STRIDE + e + 4);
        ushort8 o;
        o[0] = f2bf(a0 * p0.x + a1 * q0.x + a2 * r0.x + a3 * s0.x);
        o[1] = f2bf(a0 * p0.y + a1 * q0.y + a2 * r0.y + a3 * s0.y);
        o[2] = f2bf(a0 * p0.z + a1 * q0.z + a2 * r0.z + a3 * s0.z);
        o[3] = f2bf(a0 * p0.w + a1 * q0.w + a2 * r0.w + a3 * s0.w);
        o[4] = f2bf(a0 * p1.x + a1 * q1.x + a2 * r1.x + a3 * s1.x);
        o[5] = f2bf(a0 * p1.y + a1 * q1.y + a2 * r1.y + a3 * s1.y);
        o[6] = f2bf(a0 * p1.z + a1 * q1.z + a2 * r1.z + a3 * s1.z);
        o[7] = f2bf(a0 * p1.w + a1 * q1.w + a2 * r1.w + a3 * s1.w);
        *(ushort8*)(Wb + e) = o;
    } else {
        const long e = ((long)(bid - 8192) * 256 + threadIdx.x) * 8;
        const float4 v0 = *(const float4*)(x + e);
        const float4 v1 = *(const float4*)(x + e + 4);
        ushort8 o;
        o[0] = f2bf(v0.x); o[1] = f2bf(v0.y); o[2] = f2bf(v0.z); o[3] = f2bf(v0.w);
        o[4] = f2bf(v1.x); o[5] = f2bf(v1.y); o[6] = f2bf(v1.z); o[7] = f2bf(v1.w);
        *(ushort8*)(Xb + e) = o;
    }
}

// ---------------------------------------------------------------------------
// Main GEMM: C[m][n] = sum_k A[m][k] * Bt[n][k]   (A=Xbf16, Bt=Wbf16)
// 128x128 block tile, 256 threads (4 waves, 2x2 of 64x64), BK=32,
// 32x32x16 bf16 MFMA (2x2 accs/wave), reg-staged double-buffered LDS,
// ONE barrier per K-iter (R3/R5 pipeline, best measured).
//
// R6: LDS bank conflicts eliminated by PADDED ROW STRIDE instead of XOR
// swizzle: row stride = 40 elements (80 B = 20 banks). For any fixed 16B
// chunk, banks(l) = (20*l + const) mod 32 cycles through all 8 bank-quads
// every 8 lanes -> provably conflict-free reads at any HW granularity.
// Writes (4 threads/row, chunks 0-3) are at worst 2-way aliased = free
// (m136). No address XOR math on either side. LDS = 40 KB -> 4 blocks/CU.
//
// Block mapping: plain 2D grid (blockIdx.x = n-tile, y = m-tile), the
// measured-164MB-FETCH config from R2-R4 (R5's XCD swizzle tripled fetch).
//
// 32x32x16 layouts (HW-verified R5, absmax 4.0): A/B operand m(/n)=lane&31,
// k=(lane>>5)*8+j; C/D col=lane&31, row=(r&3)+8*(r>>2)+4*(lane>>5).
// ---------------------------------------------------------------------------
__global__ __launch_bounds__(256, 4) void gemm_bt_kernel(
        const unsigned short* __restrict__ A, const unsigned short* __restrict__ Bt,
        float* __restrict__ C) {
    __shared__ unsigned short sA[2 * 128 * RS];
    __shared__ unsigned short sB[2 * 128 * RS];

    const int t = threadIdx.x;
    const int wave = t >> 6, lane = t & 63;
    const int wm = (wave >> 1) * 64;   // wave row offset in tile
    const int wn = (wave & 1) * 64;    // wave col offset in tile
    const int l31 = lane & 31, g = lane >> 5;

    const int mBase = blockIdx.y * 128;
    const int nBase = blockIdx.x * 128;

    // Staging: thread t owns (row = t>>2, chunk = t&3) and row+64 of each tile.
    const int srow = t >> 2;           // 0..63
    const int sch = (t & 3) * 8;       // chunk offset in elements
    const unsigned short* gA0 = A + (size_t)(mBase + srow) * DIM_K + sch;
    const unsigned short* gA1 = gA0 + (size_t)64 * DIM_K;
    const unsigned short* gB0 = Bt + (size_t)(nBase + srow) * DIM_K + sch;
    const unsigned short* gB1 = gB0 + (size_t)64 * DIM_K;
    const int lo0 = srow * RS + sch;          // LDS offset row srow
    const int lo1 = (64 + srow) * RS + sch;   // LDS offset row srow+64

    // Fragment read row offsets (elements) within one buffer.
    const int arow = (wm + l31) * RS;
    const int brow = (wn + l31) * RS;

    floatx16 acc[2][2] = {};

    // ---- prologue: tile 0 -> regs -> LDS buf 0 ----
    ushort8 rA0 = *(const ushort8*)gA0;
    ushort8 rA1 = *(const ushort8*)gA1;
    ushort8 rB0 = *(const ushort8*)gB0;
    ushort8 rB1 = *(const ushort8*)gB1;
    gA0 += 32; gA1 += 32; gB0 += 32; gB1 += 32;
    *(ushort8*)(sA + lo0) = rA0;
    *(ushort8*)(sA + lo1) = rA1;
    *(ushort8*)(sB + lo0) = rB0;
    *(ushort8*)(sB + lo1) = rB1;
    __syncthreads();

    int p = 0;
    for (int kt = 0; kt < DIM_K; kt += 32) {
        const bool more = (kt + 32) < DIM_K;
        if (more) {
            rA0 = *(const ushort8*)gA0;
            rA1 = *(const ushort8*)gA1;
            rB0 = *(const ushort8*)gB0;
            rB1 = *(const ushort8*)gB1;
            gA0 += 32; gA1 += 32; gB0 += 32; gB1 += 32;
        }

        const unsigned short* bufA = sA + p * (128 * RS);
        const unsigned short* bufB = sB + p * (128 * RS);
        bf16x8 a[2][2], b[2][2];
#pragma unroll
        for (int i = 0; i < 2; i++) {
            a[i][0] = *(const bf16x8*)(bufA + arow + i * 32 * RS + (0 + g) * 8);
            a[i][1] = *(const bf16x8*)(bufA + arow + i * 32 * RS + (2 + g) * 8);
        }
#pragma unroll
        for (int j = 0; j < 2; j++) {
            b[j][0] = *(const bf16x8*)(bufB + brow + j * 32 * RS + (0 + g) * 8);
            b[j][1] = *(const bf16x8*)(bufB + brow + j * 32 * RS + (2 + g) * 8);
        }

#pragma unroll
        for (int h = 0; h < 2; h++)
#pragma unroll
            for (int i = 0; i < 2; i++)
#pragma unroll
                for (int j = 0; j < 2; j++)
                    acc[i][j] = __builtin_amdgcn_mfma_f32_32x32x16_bf16(
                        a[i][h], b[j][h], acc[i][j], 0, 0, 0);

        if (more) {
            unsigned short* wA = sA + (p ^ 1) * (128 * RS);
            unsigned short* wB = sB + (p ^ 1) * (128 * RS);
            *(ushort8*)(wA + lo0) = rA0;          // vmcnt wait lands here,
            *(ushort8*)(wA + lo1) = rA1;          // after the MFMA block
            *(ushort8*)(wB + lo0) = rB0;
            *(ushort8*)(wB + lo1) = rB1;
        }
        __syncthreads();   // single barrier per iter
        p ^= 1;
    }

    // Epilogue: 32x32 C/D layout col=lane&31, row=(r&3)+8*(r>>2)+4*g
#pragma unroll
    for (int i = 0; i < 2; i++) {
#pragma unroll
        for (int j = 0; j < 2; j++) {
#pragma unroll
            for (int r = 0; r < 16; r++) {
                const int row = mBase + wm + i * 32 + (r & 3) + 8 * (r >> 2) + 4 * g;
                const int col = nBase + wn + j * 32 + l31;
                C[(size_t)row * DIM_N + col] = acc[i][j][r];
            }
        }
    }
}

// ---------------------------------------------------------------------------
// Fallback (only if workspace too small): direct fp32, one thread per output
// ---------------------------------------------------------------------------
__global__ __launch_bounds__(256) void naive_kernel(
        const float* __restrict__ x, const float* __restrict__ alphas,
        const int* __restrict__ bases, float* __restrict__ out) {
    const long o = (long)blockIdx.x * 256 + threadIdx.x;
    const int m = (int)(o >> 12), n = (int)(o & 4095);
    const float a0 = alphas[0], a1 = alphas[1], a2 = alphas[2], a3 = alphas[3];
    const float* xr = x + (long)m * DIM_K;
    const int* b0 = bases + (long)n * DIM_K;
    const int* b1 = b0 + BASE_STRIDE;
    const int* b2 = b1 + BASE_STRIDE;
    const int* b3 = b2 + BASE_STRIDE;
    float acc = 0.f;
    for (int i = 0; i < DIM_K; i++) {
        float w = a0 * b0[i] + a1 * b1[i] + a2 * b2[i] + a3 * b3[i];
        acc += xr[i] * w;
    }
    out[o] = acc;
}

extern "C" void kernel_launch(void* const* d_in, const int* in_sizes, int n_in,
                              void* d_out, int out_size, void* d_ws, size_t ws_size,
                              hipStream_t stream) {
    const float* x      = (const float*)d_in[0];
    const float* alphas = (const float*)d_in[1];
    const int*   bases  = (const int*)d_in[2];
    float* out = (float*)d_out;

    const size_t need = (size_t)2 * DIM_N * DIM_K + (size_t)2 * DIM_M * DIM_K; // 64 MB
    if (ws_size >= need) {
        unsigned short* Wb = (unsigned short*)d_ws;                    // [4096][4096] bf16
        unsigned short* Xb = (unsigned short*)d_ws + (size_t)DIM_N * DIM_K;
        prep_kernel<<<16384, 256, 0, stream>>>(bases, alphas, x, Wb, Xb);
        gemm_bt_kernel<<<dim3(DIM_N / 128, DIM_M / 128), 256, 0, stream>>>(Xb, Wb, out);
    } else {
        naive_kernel<<<(DIM_M * DIM_N) / 256, 256, 0, stream>>>(x, alphas, bases, out);
    }
}